// Round 14
// baseline (491.816 us; speedup 1.0000x reference)
//
#include <hip/hip_runtime.h>
#include <hip/hip_bf16.h>

namespace {
constexpr int Bn = 512;
constexpr int Ln = 1024;
constexpr int Vn = 64;
constexpr int En = 128;
constexpr int Kc = Vn + En;              // 192
constexpr size_t SEQB_BYTES  = (size_t)Bn * Ln * Vn * 2;  // 67,108,864
constexpr size_t WALLB_BYTES = (size_t)En * Kc * 2;       // 49,152
constexpr size_t BC_BYTES    = En * 4;                    // 512
constexpr size_t WOUTP_BYTES = (size_t)Vn * En * 2;       // 16,384
constexpr size_t FAST_WS  = SEQB_BYTES + WALLB_BYTES + BC_BYTES;               // LDS path
constexpr size_t FAST_WS2 = SEQB_BYTES + WALLB_BYTES + BC_BYTES + WOUTP_BYTES; // 32x32 path
}

typedef __attribute__((ext_vector_type(8))) short bf16x8;
typedef __attribute__((ext_vector_type(4))) float f32x4;
typedef __attribute__((ext_vector_type(16))) float f32x16;
typedef __attribute__((ext_vector_type(8))) unsigned short u16x8;

__device__ __forceinline__ unsigned f2b(float f) {
  unsigned u = __float_as_uint(f);
  u += 0x7fffu + ((u >> 16) & 1u);
  return u >> 16;
}
__device__ __forceinline__ float b2f(unsigned short b) {
  return __uint_as_float(((unsigned)b) << 16);
}
__device__ __forceinline__ bf16x8 pack8(const float* v) {
  bf16x8 r;
#pragma unroll
  for (int i = 0; i < 8; ++i) r[i] = (short)f2b(v[i]);
  return r;
}

// 32x32x16 h-cycle permutation: z k index kk (0..127) -> h column.
// Wave w C reg r at lane(c,hi) holds h col 32w + (r&3)+8*(r>>2)+4*hi; packed reg i
// of tile 2w+u = B-frag elem (hi,i) = kk = 16*(2w+u)+8hi+i. Identity requires:
// cm32(kk) = 16*(kk>>4) + 8*((kk>>2)&1) + 4*((kk>>3)&1) + (kk&3)
__device__ __forceinline__ int cm32(int kk) {
  return 16 * (kk >> 4) + 8 * ((kk >> 2) & 1) + 4 * ((kk >> 3) & 1) + (kk & 3);
}

#define MFMA16 __builtin_amdgcn_mfma_f32_16x16x32_bf16
#define MFMA32 __builtin_amdgcn_mfma_f32_32x32x16_bf16

// ---------------- setup kernels ----------------

__global__ void seq_cvt(const float* __restrict__ seq, unsigned short* __restrict__ seqb) {
  const size_t n = (size_t)Bn * Ln * Vn;
  size_t i = ((size_t)blockIdx.x * blockDim.x + threadIdx.x) * 8;
  const size_t stride = (size_t)gridDim.x * blockDim.x * 8;
  for (; i < n; i += stride) {
    const f32x4 a = *(const f32x4*)(seq + i);
    const f32x4 b = *(const f32x4*)(seq + i + 4);
    u16x8 o;
#pragma unroll
    for (int j = 0; j < 4; ++j) o[j] = (unsigned short)f2b(a[j]);
#pragma unroll
    for (int j = 0; j < 4; ++j) o[4 + j] = (unsigned short)f2b(b[j]);
    *(u16x8*)(seqb + i) = o;
  }
}

// Wall2[j][k] bf16: k<64 -> folded input proj (natural col order);
//                   k>=64 -> Whh[j][cm32(k-64)]
__global__ void rnn_setup32(const float* __restrict__ W_in, const float* __restrict__ b_in,
                            const float* __restrict__ W_h, const float* __restrict__ b_h,
                            unsigned short* __restrict__ wall2, float* __restrict__ bc) {
  const int j = blockIdx.x;    // 0..127
  const int k = threadIdx.x;   // 0..191
  const float* whr = W_h + j * (2 * En);
  float s;
  if (k < Vn) {
    s = 0.f;
#pragma unroll 8
    for (int e = 0; e < En; ++e) s = fmaf(W_in[e * Vn + k], whr[e], s);
  } else {
    s = whr[En + cm32(k - Vn)];
  }
  wall2[j * Kc + k] = (unsigned short)f2b(s);
  if (k == 0) {
    float b = b_h[j];
    for (int e = 0; e < En; ++e) b = fmaf(b_in[e], whr[e], b);
    bc[j] = b;
  }
}

__global__ void wout_setup32(const float* __restrict__ W_out, unsigned short* __restrict__ woutp) {
  const int v = blockIdx.x;    // 0..63
  const int kk = threadIdx.x;  // 0..127
  woutp[v * En + kk] = (unsigned short)f2b(W_out[(size_t)v * En + cm32(kk)]);
}

// ---------------- main kernel: 32x32x16, 32 rows/block, 4 waves ----------------
// Wave w owns h cols [32w,32w+32) = z k-tiles {2w,2w+1} (K=16 each). Its packed
// relu C regs 0..7 / 8..15 ARE its two B-frags (cm32 identity) — register
// resident. 6 foreign tiles exchanged via lane-linear LDS (l*16 slots,
// conflict-free). Per step/wave: 12 MFMA32 (4 seq + 8 z), 6 ds_read_b128,
// 2 ds_write_b128, 1 drain+barrier. 1 wave/SIMD (r8-r12: 8-wave blocks hit a
// ~1050cyc wall; 4-wave is clean). MFMA32 = 2x FLOP of MFMA16 at (bet) <2x the
// ~36cyc single-wave blocking issue cost.
__global__ __launch_bounds__(256, 1) void rnn_q32(
    const unsigned short* __restrict__ seqb, const unsigned short* __restrict__ wall2,
    const float* __restrict__ bc, const unsigned short* __restrict__ woutp,
    const float* __restrict__ b_out, float* __restrict__ out) {
  __shared__ __align__(16) unsigned char zb[2][8][1024];  // [buf][tile][lane*16B]

  const int tid = threadIdx.x;
  const int w   = tid >> 6;        // wave 0..3, owns h cols 32w..32w+31
  const int l   = tid & 63;
  const int c   = l & 31;          // batch col (C/D and B col)
  const int hi  = l >> 5;          // k/reg-group half
  const int r0  = blockIdx.x * 32;

  // ---- A-frags: j = 32w + c, k-elem = 8hi + i ----
  bf16x8 Aws[4], Awz[8];  // Awz[p] = z k-tile (2w+p)&7  (p=0,1 own)
  {
    const unsigned short* rowp = wall2 + (size_t)(32 * w + c) * Kc + hi * 8;
#pragma unroll
    for (int kt = 0; kt < 4; ++kt) Aws[kt] = *(const bf16x8*)(rowp + 16 * kt);
#pragma unroll
    for (int p = 0; p < 8; ++p)
      Awz[p] = *(const bf16x8*)(rowp + Vn + 16 * ((2 * w + p) & 7));
  }

  // ---- bias in C-reg layout: bcv[r] = bc[32w + (r&3) + 8*(r>>2) + 4*hi] ----
  f32x16 bcv;
#pragma unroll
  for (int r = 0; r < 16; ++r) bcv[r] = bc[32 * w + (r & 3) + 8 * (r >> 2) + 4 * hi];

  // ---- LDS offsets (lane-linear, conflict-free) ----
  const int ro = l * 16;
  const int wo0 = ((2 * w) & 7) * 1024 + ro;
  const int wo1 = ((2 * w + 1) & 7) * 1024 + ro;
  int rof[6];
#pragma unroll
  for (int p = 0; p < 6; ++p) rof[p] = ((2 * w + 2 + p) & 7) * 1024 + ro;

  // h(0) = 0
  for (int i = tid; i < 4096; i += 256) ((unsigned int*)zb)[i] = 0u;
  bf16x8 zown0, zown1;
#pragma unroll
  for (int i = 0; i < 8; ++i) { zown0[i] = 0; zown1[i] = 0; }

  // seq source: batch row r0+c, elem offset 8hi; frag kt at +16kt
  const unsigned short* sqb = seqb + ((size_t)(r0 + c) * Ln) * Vn + hi * 8;
  bf16x8 sreg[4][4];

#define SEQ_PF(BI, T)                                                 \
  { const int tp = ((T) < Ln) ? (T) : (Ln - 1);                       \
    const unsigned short* sp = sqb + (size_t)tp * Vn;                 \
    sreg[BI][0] = *(const bf16x8*)(sp);                               \
    sreg[BI][1] = *(const bf16x8*)(sp + 16);                          \
    sreg[BI][2] = *(const bf16x8*)(sp + 32);                          \
    sreg[BI][3] = *(const bf16x8*)(sp + 48); }

  SEQ_PF(0, 0)
  SEQ_PF(1, 1)
  SEQ_PF(2, 2)
  __syncthreads();

#define PHASE(P)                                                              \
  {                                                                           \
    const int cb = (P) & 1, nb = cb ^ 1;                                      \
    const unsigned char* base = (const unsigned char*)zb + cb * 8192;         \
    const bf16x8 zf0 = *(const bf16x8*)(base + rof[0]);                       \
    const bf16x8 zf1 = *(const bf16x8*)(base + rof[1]);                       \
    const bf16x8 zf2 = *(const bf16x8*)(base + rof[2]);                       \
    const bf16x8 zf3 = *(const bf16x8*)(base + rof[3]);                       \
    const bf16x8 zf4 = *(const bf16x8*)(base + rof[4]);                       \
    const bf16x8 zf5 = *(const bf16x8*)(base + rof[5]);                       \
    SEQ_PF(((P) + 3) & 3, t + (P) + 3);                                       \
    f32x16 accQ = {0.f, 0.f, 0.f, 0.f, 0.f, 0.f, 0.f, 0.f,                    \
                   0.f, 0.f, 0.f, 0.f, 0.f, 0.f, 0.f, 0.f};                   \
    f32x16 accP = MFMA32(Aws[0], sreg[(P)][0], bcv, 0, 0, 0);                 \
    accQ = MFMA32(Aws[1], sreg[(P)][1], accQ, 0, 0, 0);                       \
    accP = MFMA32(Aws[2], sreg[(P)][2], accP, 0, 0, 0);                       \
    accQ = MFMA32(Aws[3], sreg[(P)][3], accQ, 0, 0, 0);                       \
    accP = MFMA32(Awz[0], zown0, accP, 0, 0, 0);                              \
    accQ = MFMA32(Awz[1], zown1, accQ, 0, 0, 0);                              \
    accP = MFMA32(Awz[2], zf0, accP, 0, 0, 0);                                \
    accQ = MFMA32(Awz[3], zf1, accQ, 0, 0, 0);                                \
    accP = MFMA32(Awz[4], zf2, accP, 0, 0, 0);                                \
    accQ = MFMA32(Awz[5], zf3, accQ, 0, 0, 0);                                \
    accP = MFMA32(Awz[6], zf4, accP, 0, 0, 0);                                \
    accQ = MFMA32(Awz[7], zf5, accQ, 0, 0, 0);                                \
    float aa[16];                                                             \
    _Pragma("unroll") for (int r = 0; r < 16; ++r)                            \
        aa[r] = fmaxf(accP[r] + accQ[r], 0.f);                                \
    unsigned u0, u1, u2, u3, u4, u5, u6, u7;                                  \
    asm("v_cvt_pk_bf16_f32 %0, %1, %2" : "=v"(u0) : "v"(aa[0]), "v"(aa[1]));  \
    asm("v_cvt_pk_bf16_f32 %0, %1, %2" : "=v"(u1) : "v"(aa[2]), "v"(aa[3]));  \
    asm("v_cvt_pk_bf16_f32 %0, %1, %2" : "=v"(u2) : "v"(aa[4]), "v"(aa[5]));  \
    asm("v_cvt_pk_bf16_f32 %0, %1, %2" : "=v"(u3) : "v"(aa[6]), "v"(aa[7]));  \
    asm("v_cvt_pk_bf16_f32 %0, %1, %2" : "=v"(u4) : "v"(aa[8]), "v"(aa[9]));  \
    asm("v_cvt_pk_bf16_f32 %0, %1, %2" : "=v"(u5) : "v"(aa[10]), "v"(aa[11]));\
    asm("v_cvt_pk_bf16_f32 %0, %1, %2" : "=v"(u6) : "v"(aa[12]), "v"(aa[13]));\
    asm("v_cvt_pk_bf16_f32 %0, %1, %2" : "=v"(u7) : "v"(aa[14]), "v"(aa[15]));\
    union { unsigned u[4]; bf16x8 v; } z0_, z1_;                              \
    z0_.u[0] = u0; z0_.u[1] = u1; z0_.u[2] = u2; z0_.u[3] = u3;               \
    z1_.u[0] = u4; z1_.u[1] = u5; z1_.u[2] = u6; z1_.u[3] = u7;               \
    zown0 = z0_.v;                                                            \
    zown1 = z1_.v;                                                            \
    unsigned char* wbase = (unsigned char*)zb + nb * 8192;                    \
    *(bf16x8*)(wbase + wo0) = zown0;                                          \
    *(bf16x8*)(wbase + wo1) = zown1;                                          \
    asm volatile("s_waitcnt lgkmcnt(0)" ::: "memory");                        \
    __builtin_amdgcn_s_barrier();                                             \
    asm volatile("" ::: "memory");                                            \
  }

#pragma unroll 1
  for (int t = 0; t < Ln; t += 4) {
    PHASE(0)
    PHASE(1)
    PHASE(2)
    PHASE(3)
  }
#undef PHASE
#undef SEQ_PF

  // ---- epilogue: h(1024) in zb[0] (step 1023 wrote nb=0). Waves 0,1 -> vocab
  // tiles 0,1: out = h @ W_out^T + b_out via 8 chained MFMA32. ----
  if (w < 2) {
    const unsigned short* wrow = woutp + (size_t)(32 * w + c) * En + hi * 8;
    f32x16 oacc;
#pragma unroll
    for (int r = 0; r < 16; ++r) oacc[r] = b_out[32 * w + (r & 3) + 8 * (r >> 2) + 4 * hi];
#pragma unroll
    for (int tau = 0; tau < 8; ++tau) {
      const bf16x8 zt = *(const bf16x8*)((const unsigned char*)zb + tau * 1024 + ro);
      const bf16x8 wf = *(const bf16x8*)(wrow + 16 * tau);
      oacc = MFMA32(wf, zt, oacc, 0, 0, 0);
    }
#pragma unroll
    for (int r = 0; r < 16; ++r)
      out[(size_t)(r0 + c) * Vn + 32 * w + (r & 3) + 8 * (r >> 2) + 4 * hi] = oacc[r];
  }
}

// ---------------- round-6 LDS fast path (fallback #1) ----------------

__global__ void rnn_setup_bf(const float* __restrict__ W_in, const float* __restrict__ b_in,
                             const float* __restrict__ W_h, const float* __restrict__ b_h,
                             unsigned short* __restrict__ wallb, float* __restrict__ bc) {
  const int j = blockIdx.x;
  const int k = threadIdx.x;
  const float* whr = W_h + j * (2 * En);
  float s;
  if (k < Vn) {
    s = 0.f;
#pragma unroll 8
    for (int e = 0; e < En; ++e) s = fmaf(W_in[e * Vn + k], whr[e], s);
  } else {
    s = whr[Vn + k];
  }
  wallb[j * Kc + k] = (unsigned short)f2b(s);
  if (k == 0) {
    float b = b_h[j];
    for (int e = 0; e < En; ++e) b = fmaf(b_in[e], whr[e], b);
    bc[j] = b;
  }
}

__global__ __launch_bounds__(128, 1) void rnn_fast2(
    const unsigned short* __restrict__ seqb, const unsigned short* __restrict__ wallb,
    const float* __restrict__ bc, const float* __restrict__ W_out,
    const float* __restrict__ b_out, float* __restrict__ out) {
  __shared__ __align__(16) unsigned char hbB[2][4096];

  const int tid = threadIdx.x;
  const int w   = tid >> 6;
  const int l   = tid & 63;
  const int l15 = l & 15;
  const int lg  = l >> 4;
  const int r0  = blockIdx.x * 16;
  const int swz = (l15 & 7) << 4;

  bf16x8 Aw[4][6];
  f32x4 bcv[4];
#pragma unroll
  for (int nn = 0; nn < 4; ++nn) {
    const int n = 4 * w + nn;
    const unsigned short* p = wallb + (size_t)(16 * n + l15) * Kc + lg * 8;
#pragma unroll
    for (int kt = 0; kt < 6; ++kt) Aw[nn][kt] = *(const bf16x8*)(p + kt * 32);
    bcv[nn] = *(const f32x4*)(bc + 16 * n + 4 * lg);
  }

  for (int i = tid; i < 2048; i += 128) ((unsigned int*)hbB)[i] = 0u;

  const unsigned short* sqb = seqb + ((size_t)(r0 + l15) * Ln) * Vn + lg * 8;
  bf16x8 sreg[4][2];

#define SEQ_PF(BI, T)                                                \
  { const int tp = ((T) < Ln) ? (T) : (Ln - 1);                      \
    const bf16x8* sp = (const bf16x8*)(sqb + (size_t)tp * Vn);       \
    sreg[BI][0] = sp[0];                                             \
    sreg[BI][1] = sp[4]; }

  SEQ_PF(0, 0)
  SEQ_PF(1, 1)
  SEQ_PF(2, 2)
  __syncthreads();

#define PHASE(P)                                                               \
  {                                                                            \
    const int cb = (P) & 1;                                                    \
    const unsigned char* zbp = hbB[cb] + l15 * 256;                            \
    const bf16x8 z0 = *(const bf16x8*)(zbp + ((16 * lg) ^ swz));               \
    const bf16x8 z1 = *(const bf16x8*)(zbp + ((64 + 16 * lg) ^ swz));          \
    const bf16x8 z2 = *(const bf16x8*)(zbp + ((128 + 16 * lg) ^ swz));         \
    const bf16x8 z3 = *(const bf16x8*)(zbp + ((192 + 16 * lg) ^ swz));         \
    SEQ_PF(((P) + 3) & 3, t + (P) + 3);                                        \
    const bf16x8 s0 = sreg[(P)][0], s1 = sreg[(P)][1];                         \
    f32x4 p0 = bcv[0], p1 = bcv[1], p2 = bcv[2], p3 = bcv[3];                  \
    f32x4 q0 = {0.f, 0.f, 0.f, 0.f}, q1 = {0.f, 0.f, 0.f, 0.f};                \
    f32x4 q2 = {0.f, 0.f, 0.f, 0.f}, q3 = {0.f, 0.f, 0.f, 0.f};                \
    p0 = MFMA16(Aw[0][0], s0, p0, 0, 0, 0);                                    \
    p1 = MFMA16(Aw[1][0], s0, p1, 0, 0, 0);                                    \
    p2 = MFMA16(Aw[2][0], s0, p2, 0, 0, 0);                                    \
    p3 = MFMA16(Aw[3][0], s0, p3, 0, 0, 0);                                    \
    q0 = MFMA16(Aw[0][1], s1, q0, 0, 0, 0);                                    \
    q1 = MFMA16(Aw[1][1], s1, q1, 0, 0, 0);                                    \
    q2 = MFMA16(Aw[2][1], s1, q2, 0, 0, 0);                                    \
    q3 = MFMA16(Aw[3][1], s1, q3, 0, 0, 0);                                    \
    p0 = MFMA16(Aw[0][2], z0, p0, 0, 0, 0);                                    \
    p1 = MFMA16(Aw[1][2], z0, p1, 0, 0, 0);                                    \
    p2 = MFMA16(Aw[2][2], z0, p2, 0, 0, 0);                                    \
    p3 = MFMA16(Aw[3][2], z0, p3, 0, 0, 0);                                    \
    q0 = MFMA16(Aw[0][3], z1, q0, 0, 0, 0);                                    \
    q1 = MFMA16(Aw[1][3], z1, q1, 0, 0, 0);                                    \
    q2 = MFMA16(Aw[2][3], z1, q2, 0, 0, 0);                                    \
    q3 = MFMA16(Aw[3][3], z1, q3, 0, 0, 0);                                    \
    p0 = MFMA16(Aw[0][4], z2, p0, 0, 0, 0);                                    \
    p1 = MFMA16(Aw[1][4], z2, p1, 0, 0, 0);                                    \
    p2 = MFMA16(Aw[2][4], z2, p2, 0, 0, 0);                                    \
    p3 = MFMA16(Aw[3][4], z2, p3, 0, 0, 0);                                    \
    q0 = MFMA16(Aw[0][5], z3, q0, 0, 0, 0);                                    \
    q1 = MFMA16(Aw[1][5], z3, q1, 0, 0, 0);                                    \
    q2 = MFMA16(Aw[2][5], z3, q2, 0, 0, 0);                                    \
    q3 = MFMA16(Aw[3][5], z3, q3, 0, 0, 0);                                    \
    unsigned char* wbB = hbB[cb ^ 1] + l15 * 256;                              \
    _Pragma("unroll") for (int nn = 0; nn < 4; ++nn) {                         \
      const f32x4 pp = (nn == 0) ? p0 : (nn == 1) ? p1 : (nn == 2) ? p2 : p3;  \
      const f32x4 qq = (nn == 0) ? q0 : (nn == 1) ? q1 : (nn == 2) ? q2 : q3;  \
      const float r0v = fmaxf(pp[0] + qq[0], 0.f);                             \
      const float r1v = fmaxf(pp[1] + qq[1], 0.f);                             \
      const float r2v = fmaxf(pp[2] + qq[2], 0.f);                             \
      const float r3v = fmaxf(pp[3] + qq[3], 0.f);                             \
      unsigned d0, d1;                                                         \
      asm("v_cvt_pk_bf16_f32 %0, %1, %2" : "=v"(d0) : "v"(r0v), "v"(r1v));     \
      asm("v_cvt_pk_bf16_f32 %0, %1, %2" : "=v"(d1) : "v"(r2v), "v"(r3v));     \
      uint2 dd; dd.x = d0; dd.y = d1;                                          \
      *(uint2*)(wbB + ((128 * w + 32 * nn + 8 * lg) ^ swz)) = dd;              \
    }                                                                          \
    asm volatile("s_waitcnt lgkmcnt(0)" ::: "memory");                         \
    __builtin_amdgcn_s_barrier();                                              \
    asm volatile("" ::: "memory");                                             \
  }

#pragma unroll 1
  for (int t = 0; t < Ln; t += 4) {
    PHASE(0)
    PHASE(1)
    PHASE(2)
    PHASE(3)
  }
#undef PHASE
#undef SEQ_PF

  bf16x8 hz[4];
  const unsigned char* zb0 = hbB[0] + l15 * 256;
#pragma unroll
  for (int kt = 0; kt < 4; ++kt)
    hz[kt] = *(const bf16x8*)(zb0 + ((64 * kt + 16 * lg) ^ swz));
#pragma unroll
  for (int m = 0; m < 2; ++m) {
    const int v = 16 * (2 * w + m) + l15;
    const float* wor = W_out + (size_t)v * En + lg * 8;
    const float bo = b_out[v];
    f32x4 oa = {bo, bo, bo, bo};
#pragma unroll
    for (int kt = 0; kt < 4; ++kt) {
      float tmp[8];
      const float* p = wor + kt * 32;
#pragma unroll
      for (int i = 0; i < 8; ++i) tmp[i] = p[i];
      oa = MFMA16(hz[kt], pack8(tmp), oa, 0, 0, 0);
    }
#pragma unroll
    for (int i = 0; i < 4; ++i)
      out[(size_t)(r0 + 4 * lg + i) * Vn + v] = oa[i];
  }
}

// ---------------- fp32 fallback (no workspace needed) ----------------

__global__ __launch_bounds__(256, 1) void rnn_mfma(
    const float* __restrict__ seq, const float* __restrict__ W_in,
    const float* __restrict__ b_in, const float* __restrict__ W_h,
    const float* __restrict__ b_h, const float* __restrict__ W_out,
    const float* __restrict__ b_out, float* __restrict__ out) {
  __shared__ __align__(16) unsigned short hb[2][16][136];

  const int tid = threadIdx.x;
  const int w   = tid >> 6;
  const int l   = tid & 63;
  const int l15 = l & 15;
  const int lg  = l >> 4;
  const int r0  = blockIdx.x * 16;

  bf16x8 Bw[2][6];
  float bc[2];
#pragma unroll
  for (int n = 0; n < 2; ++n) {
    const int j = 32 * w + 16 * n + l15;
    const float* whr = W_h + j * (2 * En);
    float b = b_h[j];
    for (int e = 0; e < En; ++e) b = fmaf(b_in[e], whr[e], b);
    bc[n] = b;
#pragma unroll
    for (int kt = 0; kt < 6; ++kt) {
      float v[8];
#pragma unroll
      for (int i = 0; i < 8; ++i) {
        const int k = kt * 32 + lg * 8 + i;
        if (k < Vn) {
          float s = 0.f;
          for (int e = 0; e < En; ++e) s = fmaf(W_in[e * Vn + k], whr[e], s);
          v[i] = s;
        } else {
          v[i] = whr[Vn + k];
        }
      }
      Bw[n][kt] = pack8(v);
    }
  }

  for (int i = tid; i < 2 * 16 * 136; i += 256) ((unsigned short*)hb)[i] = 0;

  const float* sq = seq + ((size_t)(r0 + l15) * Ln) * Vn + lg * 8;
  f32x4 sbuf[4][4];

#define SEQ_PF(BI, T)                                                 \
  { const int tp = ((T) < Ln) ? (T) : (Ln - 1);                       \
    const f32x4* p0 = (const f32x4*)(sq + (size_t)tp * Vn);           \
    const f32x4* p1 = (const f32x4*)(sq + (size_t)tp * Vn + 32);      \
    sbuf[BI][0] = p0[0]; sbuf[BI][1] = p0[1];                         \
    sbuf[BI][2] = p1[0]; sbuf[BI][3] = p1[1]; }

  SEQ_PF(0, 0)
  SEQ_PF(1, 1)
  SEQ_PF(2, 2)
  __syncthreads();

#define PHASE(P)                                                              \
  {                                                                           \
    const int cb = (P) & 1, nb = cb ^ 1;                                      \
    const bf16x8 h0 = *(const bf16x8*)&hb[cb][l15][lg * 8];                   \
    const bf16x8 h1 = *(const bf16x8*)&hb[cb][l15][32 + lg * 8];              \
    const bf16x8 h2 = *(const bf16x8*)&hb[cb][l15][64 + lg * 8];              \
    const bf16x8 h3 = *(const bf16x8*)&hb[cb][l15][96 + lg * 8];              \
    SEQ_PF(((P) + 3) & 3, t + (P) + 3);                                       \
    float v0[8], v1[8];                                                       \
    _Pragma("unroll") for (int i = 0; i < 4; ++i) {                           \
      v0[i] = sbuf[(P)][0][i]; v0[4 + i] = sbuf[(P)][1][i];                   \
      v1[i] = sbuf[(P)][2][i]; v1[4 + i] = sbuf[(P)][3][i];                   \
    }                                                                         \
    const bf16x8 a0 = pack8(v0), a1 = pack8(v1);                              \
    f32x4 p0a = {bc[0], bc[0], bc[0], bc[0]};                                 \
    f32x4 p1a = {bc[1], bc[1], bc[1], bc[1]};                                 \
    f32x4 q0a = {0.f, 0.f, 0.f, 0.f}, q1a = {0.f, 0.f, 0.f, 0.f};             \
    p0a = MFMA16(a0, Bw[0][0], p0a, 0, 0, 0);                                 \
    p1a = MFMA16(a0, Bw[1][0], p1a, 0, 0, 0);                                 \
    p0a = MFMA16(a1, Bw[0][1], p0a, 0, 0, 0);                                 \
    p1a = MFMA16(a1, Bw[1][1], p1a, 0, 0, 0);                                 \
    p0a = MFMA16(h0, Bw[0][2], p0a, 0, 0, 0);                                 \
    p1a = MFMA16(h0, Bw[1][2], p1a, 0, 0, 0);                                 \
    q0a = MFMA16(h2, Bw[0][4], q0a, 0, 0, 0);                                 \
    q1a = MFMA16(h2, Bw[1][4], q1a, 0, 0, 0);                                 \
    p0a = MFMA16(h1, Bw[0][3], p0a, 0, 0, 0);                                 \
    p1a = MFMA16(h1, Bw[1][3], p1a, 0, 0, 0);                                 \
    q0a = MFMA16(h3, Bw[0][5], q0a, 0, 0, 0);                                 \
    q1a = MFMA16(h3, Bw[1][5], q1a, 0, 0, 0);                                 \
    const int j0 = 32 * w + l15, j1 = j0 + 16, rr = 4 * lg;                   \
    _Pragma("unroll") for (int i = 0; i < 4; ++i) {                           \
      hb[nb][rr + i][j0] = (unsigned short)f2b(fmaxf(p0a[i] + q0a[i], 0.f));  \
      hb[nb][rr + i][j1] = (unsigned short)f2b(fmaxf(p1a[i] + q1a[i], 0.f));  \
    }                                                                         \
    asm volatile("s_waitcnt lgkmcnt(0)" ::: "memory");                        \
    __builtin_amdgcn_s_barrier();                                             \
    asm volatile("" ::: "memory");                                            \
  }

#pragma unroll 1
  for (int t = 0; t < Ln; t += 4) {
    PHASE(0)
    PHASE(1)
    PHASE(2)
    PHASE(3)
  }
#undef PHASE
#undef SEQ_PF

  const int orow = tid >> 4;
  const int oc   = (tid & 15) * 4;
  float o0 = b_out[oc], o1 = b_out[oc + 1], o2 = b_out[oc + 2], o3 = b_out[oc + 3];
  const float* w0 = W_out + (size_t)(oc + 0) * En;
  const float* w1 = W_out + (size_t)(oc + 1) * En;
  const float* w2 = W_out + (size_t)(oc + 2) * En;
  const float* w3 = W_out + (size_t)(oc + 3) * En;
#pragma unroll 8
  for (int k = 0; k < En; ++k) {
    const float hv = b2f(hb[0][orow][k]);
    o0 = fmaf(hv, w0[k], o0);
    o1 = fmaf(hv, w1[k], o1);
    o2 = fmaf(hv, w2[k], o2);
    o3 = fmaf(hv, w3[k], o3);
  }
  *(float4*)&out[(size_t)(r0 + orow) * Vn + oc] = make_float4(o0, o1, o2, o3);
}

extern "C" void kernel_launch(void* const* d_in, const int* in_sizes, int n_in,
                              void* d_out, int out_size, void* d_ws, size_t ws_size,
                              hipStream_t stream) {
  const float* seq   = (const float*)d_in[0];
  const float* W_in  = (const float*)d_in[1];
  const float* b_in  = (const float*)d_in[2];
  const float* W_h   = (const float*)d_in[3];
  const float* b_h   = (const float*)d_in[4];
  const float* W_out = (const float*)d_in[5];
  const float* b_out = (const float*)d_in[6];
  float* out = (float*)d_out;

  if (ws_size >= FAST_WS2) {
    unsigned short* seqb  = (unsigned short*)d_ws;
    unsigned short* wall2 = (unsigned short*)((char*)d_ws + SEQB_BYTES);
    float* bc             = (float*)((char*)d_ws + SEQB_BYTES + WALLB_BYTES);
    unsigned short* woutp = (unsigned short*)((char*)d_ws + SEQB_BYTES + WALLB_BYTES + BC_BYTES);
    seq_cvt<<<2048, 256, 0, stream>>>(seq, seqb);
    rnn_setup32<<<En, Kc, 0, stream>>>(W_in, b_in, W_h, b_h, wall2, bc);
    wout_setup32<<<Vn, En, 0, stream>>>(W_out, woutp);
    rnn_q32<<<Bn / 32, 256, 0, stream>>>(seqb, wall2, bc, woutp, b_out, out);
  } else if (ws_size >= FAST_WS) {
    unsigned short* seqb  = (unsigned short*)d_ws;
    unsigned short* wallb = (unsigned short*)((char*)d_ws + SEQB_BYTES);
    float* bc = (float*)((char*)d_ws + SEQB_BYTES + WALLB_BYTES);
    seq_cvt<<<2048, 256, 0, stream>>>(seq, seqb);
    rnn_setup_bf<<<En, Kc, 0, stream>>>(W_in, b_in, W_h, b_h, wallb, bc);
    rnn_fast2<<<Bn / 16, 128, 0, stream>>>(seqb, wallb, bc, W_out, b_out, out);
  } else {
    rnn_mfma<<<Bn / 16, 256, 0, stream>>>(seq, W_in, b_in, W_h, b_h, W_out, b_out, out);
  }
}

// Round 15
// 338.516 us; speedup vs baseline: 1.4529x; 1.4529x over previous
//
#include <hip/hip_runtime.h>
#include <hip/hip_bf16.h>

namespace {
constexpr int Bn = 512;
constexpr int Ln = 1024;
constexpr int Vn = 64;
constexpr int En = 128;
constexpr int Kc = Vn + En;              // 192
constexpr size_t SEQB_BYTES  = (size_t)Bn * Ln * Vn * 2;   // 67,108,864
constexpr size_t SP_BYTES    = (size_t)Bn * Ln * En * 2;   // 134,217,728
constexpr size_t WALLB_BYTES = (size_t)En * Kc * 2;        // 49,152
constexpr size_t BC_BYTES    = En * 4;                     // 512
constexpr size_t WOUTP_BYTES = (size_t)Vn * En * 2;        // 16,384
constexpr size_t FAST_WS  = SEQB_BYTES + WALLB_BYTES + BC_BYTES;                // LDS path
constexpr size_t FAST_WS2 = SEQB_BYTES + WALLB_BYTES + BC_BYTES + WOUTP_BYTES;  // r13 path
constexpr size_t SP_WS    = SP_BYTES + WALLB_BYTES + BC_BYTES + WOUTP_BYTES;    // sp path
}

typedef __attribute__((ext_vector_type(8))) short bf16x8;
typedef __attribute__((ext_vector_type(4))) float f32x4;
typedef __attribute__((ext_vector_type(8))) unsigned short u16x8;

__device__ __forceinline__ unsigned f2b(float f) {
  unsigned u = __float_as_uint(f);
  u += 0x7fffu + ((u >> 16) & 1u);
  return u >> 16;
}
__device__ __forceinline__ float b2f(unsigned short b) {
  return __uint_as_float(((unsigned)b) << 16);
}
__device__ __forceinline__ bf16x8 pack8(const float* v) {
  bf16x8 r;
#pragma unroll
  for (int i = 0; i < 8; ++i) r[i] = (short)f2b(v[i]);
  return r;
}

// column permutation for the h cycle (16x16x32, 4-wave):
// k-tile tau, frag elem e at k-group lg:  kk = 32*tau + 8*lg + e
// -> h col m(kk) = 32*tau + 16*(e>>2) + 4*lg + (e&3)
__device__ __forceinline__ int cm4(int kk) {
  return 32 * (kk >> 5) + 16 * ((kk >> 2) & 1) + 4 * ((kk >> 3) & 3) + (kk & 3);
}

#define MFMA __builtin_amdgcn_mfma_f32_16x16x32_bf16

// ---------------- setup kernels (shared) ----------------

__global__ void seq_cvt(const float* __restrict__ seq, unsigned short* __restrict__ seqb) {
  const size_t n = (size_t)Bn * Ln * Vn;
  size_t i = ((size_t)blockIdx.x * blockDim.x + threadIdx.x) * 8;
  const size_t stride = (size_t)gridDim.x * blockDim.x * 8;
  for (; i < n; i += stride) {
    const f32x4 a = *(const f32x4*)(seq + i);
    const f32x4 b = *(const f32x4*)(seq + i + 4);
    u16x8 o;
#pragma unroll
    for (int j = 0; j < 4; ++j) o[j] = (unsigned short)f2b(a[j]);
#pragma unroll
    for (int j = 0; j < 4; ++j) o[4 + j] = (unsigned short)f2b(b[j]);
    *(u16x8*)(seqb + i) = o;
  }
}

// Wall2[j][k] bf16: k<64 -> folded input proj (natural order); k>=64 -> Whh[j][cm4(k-64)]
__global__ void rnn_setup2(const float* __restrict__ W_in, const float* __restrict__ b_in,
                           const float* __restrict__ W_h, const float* __restrict__ b_h,
                           unsigned short* __restrict__ wall2, float* __restrict__ bc) {
  const int j = blockIdx.x;    // 0..127
  const int k = threadIdx.x;   // 0..191
  const float* whr = W_h + j * (2 * En);
  float s;
  if (k < Vn) {
    s = 0.f;
#pragma unroll 8
    for (int e = 0; e < En; ++e) s = fmaf(W_in[e * Vn + k], whr[e], s);
  } else {
    s = whr[En + cm4(k - Vn)];
  }
  wall2[j * Kc + k] = (unsigned short)f2b(s);
  if (k == 0) {
    float b = b_h[j];
    for (int e = 0; e < En; ++e) b = fmaf(b_in[e], whr[e], b);
    bc[j] = b;
  }
}

__global__ void wout_setup(const float* __restrict__ W_out, unsigned short* __restrict__ woutp) {
  const int v = blockIdx.x;    // 0..63
  const int kk = threadIdx.x;  // 0..127
  woutp[v * En + kk] = (unsigned short)f2b(W_out[(size_t)v * En + cm4(kk)]);
}

// ---------------- sp prepass: sp[t][row][j] = seq_t[row] @ Wc^T + bc ----------------
// Massively parallel (1024 blocks, all CUs). Stores bf16 in the serial kernel's
// C-register layout: slot(t,row,w,lg) holds the 8 values for lane (row%16, lg)
// of wave w: n-tiles {2w,2w+1}, regs 0..3 each.
__global__ __launch_bounds__(256) void sp_pre(
    const float* __restrict__ seq, const unsigned short* __restrict__ wall2,
    const float* __restrict__ bc, unsigned short* __restrict__ sp) {
  const int tid = threadIdx.x;
  const int w   = tid >> 6;
  const int l   = tid & 63;
  const int l15 = l & 15;
  const int lg  = l >> 4;
  const int g   = blockIdx.x >> 5;       // row-group 0..31
  const int tc  = blockIdx.x & 31;       // t-chunk 0..31 (32 t each)
  const int row = g * 16 + l15;

  bf16x8 A00, A01, A10, A11;
  {
    const unsigned short* rp0 = wall2 + (size_t)(16 * (2 * w) + l15) * Kc + lg * 8;
    const unsigned short* rp1 = wall2 + (size_t)(16 * (2 * w + 1) + l15) * Kc + lg * 8;
    A00 = *(const bf16x8*)(rp0);
    A01 = *(const bf16x8*)(rp0 + 32);
    A10 = *(const bf16x8*)(rp1);
    A11 = *(const bf16x8*)(rp1 + 32);
  }
  const f32x4 bcv0 = *(const f32x4*)(bc + 32 * w + 4 * lg);
  const f32x4 bcv1 = *(const f32x4*)(bc + 32 * w + 16 + 4 * lg);

  const float* sq = seq + ((size_t)row * Ln) * Vn + lg * 8;
#pragma unroll 4
  for (int tt = 0; tt < 32; ++tt) {
    const int t = tc * 32 + tt;
    const float* s4 = sq + (size_t)t * Vn;
    float v0[8], v1[8];
    const f32x4 a = *(const f32x4*)(s4);
    const f32x4 b = *(const f32x4*)(s4 + 4);
    const f32x4 c = *(const f32x4*)(s4 + 32);
    const f32x4 d = *(const f32x4*)(s4 + 36);
#pragma unroll
    for (int i = 0; i < 4; ++i) { v0[i] = a[i]; v0[4 + i] = b[i]; v1[i] = c[i]; v1[4 + i] = d[i]; }
    const bf16x8 s0 = pack8(v0), s1 = pack8(v1);
    f32x4 p0 = MFMA(A00, s0, bcv0, 0, 0, 0);
    p0 = MFMA(A01, s1, p0, 0, 0, 0);
    f32x4 p1 = MFMA(A10, s0, bcv1, 0, 0, 0);
    p1 = MFMA(A11, s1, p1, 0, 0, 0);
    unsigned u0, u1, u2, u3;
    asm("v_cvt_pk_bf16_f32 %0, %1, %2" : "=v"(u0) : "v"(p0[0]), "v"(p0[1]));
    asm("v_cvt_pk_bf16_f32 %0, %1, %2" : "=v"(u1) : "v"(p0[2]), "v"(p0[3]));
    asm("v_cvt_pk_bf16_f32 %0, %1, %2" : "=v"(u2) : "v"(p1[0]), "v"(p1[1]));
    asm("v_cvt_pk_bf16_f32 %0, %1, %2" : "=v"(u3) : "v"(p1[2]), "v"(p1[3]));
    union { unsigned u[4]; u16x8 v; } o;
    o.u[0] = u0; o.u[1] = u1; o.u[2] = u2; o.u[3] = u3;
    const size_t idx = ((((size_t)t * Bn + row) * 4 + w) * 4 + lg) * 8;
    *(u16x8*)(sp + idx) = o.v;
  }
}

// ---------------- main serial kernel: 4 waves, 8 z-MFMA/wave, sp pre-hoisted ----
__global__ __launch_bounds__(256, 1) void rnn_sp(
    const unsigned short* __restrict__ sp, const unsigned short* __restrict__ wall2,
    const unsigned short* __restrict__ woutp, const float* __restrict__ b_out,
    float* __restrict__ out) {
  __shared__ __align__(16) unsigned char zb[2][4][1024];  // [buf][tile][lane*16B]

  const int tid = threadIdx.x;
  const int w   = tid >> 6;        // wave 0..3 = owned z k-tile
  const int l   = tid & 63;
  const int l15 = l & 15;
  const int lg  = l >> 4;
  const int r0  = blockIdx.x * 16;

  // z-part weights only: Awz[nn][p] = n-tile 2w+nn, z k-tile (w+p)&3 (own first)
  bf16x8 Awz[2][4];
#pragma unroll
  for (int nn = 0; nn < 2; ++nn) {
    const unsigned short* row = wall2 + (size_t)(16 * (2 * w + nn) + l15) * Kc + lg * 8;
#pragma unroll
    for (int p = 0; p < 4; ++p)
      Awz[nn][p] = *(const bf16x8*)(row + Vn + 32 * ((w + p) & 3));
  }

  const int ro = l * 16;
  const unsigned char* rA1 = &zb[0][(w + 1) & 3][ro];
  const unsigned char* rA2 = &zb[0][(w + 2) & 3][ro];
  const unsigned char* rA3 = &zb[0][(w + 3) & 3][ro];
  const unsigned char* rB1 = &zb[1][(w + 1) & 3][ro];
  const unsigned char* rB2 = &zb[1][(w + 2) & 3][ro];
  const unsigned char* rB3 = &zb[1][(w + 3) & 3][ro];
  unsigned char* wA = &zb[0][w][ro];
  unsigned char* wB = &zb[1][w][ro];

  for (int i = tid; i < 2048; i += 256) ((unsigned int*)zb)[i] = 0u;
  bf16x8 zown;
#pragma unroll
  for (int i = 0; i < 8; ++i) zown[i] = 0;

  // sp lane base; per-t stride = 512*16*8 = 65536 ushorts
  const unsigned short* spl = sp + (((size_t)(r0 + l15) * 4 + w) * 4 + lg) * 8;
  u16x8 spreg[4];

#define SP_PF(BI, T)                                                  \
  { const size_t tp = ((T) < Ln) ? (size_t)(T) : (size_t)(Ln - 1);    \
    spreg[BI] = *(const u16x8*)(spl + tp * 65536); }

  SP_PF(0, 0)
  SP_PF(1, 1)
  SP_PF(2, 2)
  __syncthreads();

#define PHASE(P, R1, R2, R3, WR)                                              \
  {                                                                           \
    const bf16x8 zf1 = *(const bf16x8*)(R1);                                  \
    const bf16x8 zf2 = *(const bf16x8*)(R2);                                  \
    const bf16x8 zf3 = *(const bf16x8*)(R3);                                  \
    SP_PF(((P) + 3) & 3, t + (P) + 3);                                        \
    const u16x8 sv = spreg[(P)];                                              \
    f32x4 p0, p1;                                                             \
    p0[0] = b2f(sv[0]); p0[1] = b2f(sv[1]);                                   \
    p0[2] = b2f(sv[2]); p0[3] = b2f(sv[3]);                                   \
    p1[0] = b2f(sv[4]); p1[1] = b2f(sv[5]);                                   \
    p1[2] = b2f(sv[6]); p1[3] = b2f(sv[7]);                                   \
    f32x4 q0 = {0.f, 0.f, 0.f, 0.f}, q1 = {0.f, 0.f, 0.f, 0.f};               \
    p0 = MFMA(Awz[0][0], zown, p0, 0, 0, 0);                                  \
    p1 = MFMA(Awz[1][0], zown, p1, 0, 0, 0);                                  \
    q0 = MFMA(Awz[0][1], zf1, q0, 0, 0, 0);                                   \
    q1 = MFMA(Awz[1][1], zf1, q1, 0, 0, 0);                                   \
    p0 = MFMA(Awz[0][2], zf2, p0, 0, 0, 0);                                   \
    p1 = MFMA(Awz[1][2], zf2, p1, 0, 0, 0);                                   \
    q0 = MFMA(Awz[0][3], zf3, q0, 0, 0, 0);                                   \
    q1 = MFMA(Awz[1][3], zf3, q1, 0, 0, 0);                                   \
    const f32x4 a0 = p0 + q0, a1 = p1 + q1;                                   \
    const float x0 = fmaxf(a0[0], 0.f), x1 = fmaxf(a0[1], 0.f);               \
    const float x2 = fmaxf(a0[2], 0.f), x3 = fmaxf(a0[3], 0.f);               \
    const float y0 = fmaxf(a1[0], 0.f), y1 = fmaxf(a1[1], 0.f);               \
    const float y2 = fmaxf(a1[2], 0.f), y3 = fmaxf(a1[3], 0.f);               \
    unsigned u0, u1, u2, u3;                                                  \
    asm("v_cvt_pk_bf16_f32 %0, %1, %2" : "=v"(u0) : "v"(x0), "v"(x1));        \
    asm("v_cvt_pk_bf16_f32 %0, %1, %2" : "=v"(u1) : "v"(x2), "v"(x3));        \
    asm("v_cvt_pk_bf16_f32 %0, %1, %2" : "=v"(u2) : "v"(y0), "v"(y1));        \
    asm("v_cvt_pk_bf16_f32 %0, %1, %2" : "=v"(u3) : "v"(y2), "v"(y3));        \
    union { unsigned u[4]; bf16x8 v; } zc;                                    \
    zc.u[0] = u0; zc.u[1] = u1; zc.u[2] = u2; zc.u[3] = u3;                   \
    zown = zc.v;                                                              \
    *(bf16x8*)(WR) = zown;                                                    \
    asm volatile("s_waitcnt lgkmcnt(0)" ::: "memory");                        \
    __builtin_amdgcn_s_barrier();                                             \
    asm volatile("" ::: "memory");                                            \
  }

#pragma unroll 1
  for (int t = 0; t < Ln; t += 4) {
    PHASE(0, rA1, rA2, rA3, wB)
    PHASE(1, rB1, rB2, rB3, wA)
    PHASE(2, rA1, rA2, rA3, wB)
    PHASE(3, rB1, rB2, rB3, wA)
  }
#undef PHASE
#undef SP_PF

  // epilogue: h(1024): own tile in zown, foreign in buf0. Wave w -> vocab tile w.
  {
    const bf16x8 zf1 = *(const bf16x8*)(rA1);
    const bf16x8 zf2 = *(const bf16x8*)(rA2);
    const bf16x8 zf3 = *(const bf16x8*)(rA3);
    const unsigned short* wrow = woutp + (size_t)(16 * w + l15) * En + lg * 8;
    f32x4 o = *(const f32x4*)(b_out + 16 * w + 4 * lg);
    o = MFMA(*(const bf16x8*)(wrow + 32 * w), zown, o, 0, 0, 0);
    o = MFMA(*(const bf16x8*)(wrow + 32 * ((w + 1) & 3)), zf1, o, 0, 0, 0);
    o = MFMA(*(const bf16x8*)(wrow + 32 * ((w + 2) & 3)), zf2, o, 0, 0, 0);
    o = MFMA(*(const bf16x8*)(wrow + 32 * ((w + 3) & 3)), zf3, o, 0, 0, 0);
    *(f32x4*)&out[(size_t)(r0 + l15) * Vn + 16 * w + 4 * lg] = o;
  }
}

// ---------------- r13 kernel (fallback when ws < SP_WS) ----------------

__global__ __launch_bounds__(256, 1) void rnn_quad(
    const unsigned short* __restrict__ seqb, const unsigned short* __restrict__ wall2,
    const float* __restrict__ bc, const unsigned short* __restrict__ woutp,
    const float* __restrict__ b_out, float* __restrict__ out) {
  __shared__ __align__(16) unsigned char zlds[2][4][1024];

  const int tid = threadIdx.x;
  const int w   = tid >> 6;
  const int l   = tid & 63;
  const int l15 = l & 15;
  const int lg  = l >> 4;
  const int r0  = blockIdx.x * 16;

  bf16x8 Aw[2][6];
#pragma unroll
  for (int nn = 0; nn < 2; ++nn) {
    const unsigned short* row = wall2 + (size_t)(16 * (2 * w + nn) + l15) * Kc + lg * 8;
    Aw[nn][0] = *(const bf16x8*)(row);
    Aw[nn][1] = *(const bf16x8*)(row + 32);
#pragma unroll
    for (int p = 0; p < 4; ++p)
      Aw[nn][2 + p] = *(const bf16x8*)(row + Vn + 32 * ((w + p) & 3));
  }
  const f32x4 bcv0 = *(const f32x4*)(bc + 32 * w + 4 * lg);
  const f32x4 bcv1 = *(const f32x4*)(bc + 32 * w + 16 + 4 * lg);

  const int ro  = l * 16;
  const unsigned char* rA1 = &zlds[0][(w + 1) & 3][ro];
  const unsigned char* rA2 = &zlds[0][(w + 2) & 3][ro];
  const unsigned char* rA3 = &zlds[0][(w + 3) & 3][ro];
  const unsigned char* rB1 = &zlds[1][(w + 1) & 3][ro];
  const unsigned char* rB2 = &zlds[1][(w + 2) & 3][ro];
  const unsigned char* rB3 = &zlds[1][(w + 3) & 3][ro];
  unsigned char* wA = &zlds[0][w][ro];
  unsigned char* wB = &zlds[1][w][ro];

  for (int i = tid; i < 2048; i += 256) ((unsigned int*)zlds)[i] = 0u;
  bf16x8 zown;
#pragma unroll
  for (int i = 0; i < 8; ++i) zown[i] = 0;

  const unsigned short* sqb = seqb + ((size_t)(r0 + l15) * Ln) * Vn + lg * 8;
  bf16x8 sreg[4][2];

#define SEQ_PF(BI, T)                                                \
  { const int tp = ((T) < Ln) ? (T) : (Ln - 1);                      \
    const bf16x8* sp = (const bf16x8*)(sqb + (size_t)tp * Vn);       \
    sreg[BI][0] = sp[0];                                             \
    sreg[BI][1] = sp[4]; }

  SEQ_PF(0, 0)
  SEQ_PF(1, 1)
  SEQ_PF(2, 2)
  __syncthreads();

#define PHASE(P, R1, R2, R3, WR)                                              \
  {                                                                           \
    const bf16x8 zf1 = *(const bf16x8*)(R1);                                  \
    const bf16x8 zf2 = *(const bf16x8*)(R2);                                  \
    const bf16x8 zf3 = *(const bf16x8*)(R3);                                  \
    SEQ_PF(((P) + 3) & 3, t + (P) + 3);                                       \
    const bf16x8 s0 = sreg[(P)][0], s1 = sreg[(P)][1];                        \
    f32x4 p0 = MFMA(Aw[0][0], s0, bcv0, 0, 0, 0);                             \
    f32x4 p1 = MFMA(Aw[1][0], s0, bcv1, 0, 0, 0);                             \
    f32x4 q0 = {0.f, 0.f, 0.f, 0.f}, q1 = {0.f, 0.f, 0.f, 0.f};               \
    q0 = MFMA(Aw[0][1], s1, q0, 0, 0, 0);                                     \
    q1 = MFMA(Aw[1][1], s1, q1, 0, 0, 0);                                     \
    p0 = MFMA(Aw[0][2], zown, p0, 0, 0, 0);                                   \
    p1 = MFMA(Aw[1][2], zown, p1, 0, 0, 0);                                   \
    q0 = MFMA(Aw[0][3], zf1, q0, 0, 0, 0);                                    \
    q1 = MFMA(Aw[1][3], zf1, q1, 0, 0, 0);                                    \
    p0 = MFMA(Aw[0][4], zf2, p0, 0, 0, 0);                                    \
    p1 = MFMA(Aw[1][4], zf2, p1, 0, 0, 0);                                    \
    q0 = MFMA(Aw[0][5], zf3, q0, 0, 0, 0);                                    \
    q1 = MFMA(Aw[1][5], zf3, q1, 0, 0, 0);                                    \
    const f32x4 a0 = p0 + q0, a1 = p1 + q1;                                   \
    const float x0 = fmaxf(a0[0], 0.f), x1 = fmaxf(a0[1], 0.f);               \
    const float x2 = fmaxf(a0[2], 0.f), x3 = fmaxf(a0[3], 0.f);               \
    const float y0 = fmaxf(a1[0], 0.f), y1 = fmaxf(a1[1], 0.f);               \
    const float y2 = fmaxf(a1[2], 0.f), y3 = fmaxf(a1[3], 0.f);               \
    unsigned u0, u1, u2, u3;                                                  \
    asm("v_cvt_pk_bf16_f32 %0, %1, %2" : "=v"(u0) : "v"(x0), "v"(x1));        \
    asm("v_cvt_pk_bf16_f32 %0, %1, %2" : "=v"(u1) : "v"(x2), "v"(x3));        \
    asm("v_cvt_pk_bf16_f32 %0, %1, %2" : "=v"(u2) : "v"(y0), "v"(y1));        \
    asm("v_cvt_pk_bf16_f32 %0, %1, %2" : "=v"(u3) : "v"(y2), "v"(y3));        \
    union { unsigned u[4]; bf16x8 v; } zc;                                    \
    zc.u[0] = u0; zc.u[1] = u1; zc.u[2] = u2; zc.u[3] = u3;                   \
    zown = zc.v;                                                              \
    *(bf16x8*)(WR) = zown;                                                    \
    asm volatile("s_waitcnt lgkmcnt(0)" ::: "memory");                        \
    __builtin_amdgcn_s_barrier();                                             \
    asm volatile("" ::: "memory");                                            \
  }

#pragma unroll 1
  for (int t = 0; t < Ln; t += 4) {
    PHASE(0, rA1, rA2, rA3, wB)
    PHASE(1, rB1, rB2, rB3, wA)
    PHASE(2, rA1, rA2, rA3, wB)
    PHASE(3, rB1, rB2, rB3, wA)
  }
#undef PHASE
#undef SEQ_PF

  {
    const bf16x8 zf1 = *(const bf16x8*)(rA1);
    const bf16x8 zf2 = *(const bf16x8*)(rA2);
    const bf16x8 zf3 = *(const bf16x8*)(rA3);
    const unsigned short* wrow = woutp + (size_t)(16 * w + l15) * En + lg * 8;
    f32x4 o = *(const f32x4*)(b_out + 16 * w + 4 * lg);
    o = MFMA(*(const bf16x8*)(wrow + 32 * w), zown, o, 0, 0, 0);
    o = MFMA(*(const bf16x8*)(wrow + 32 * ((w + 1) & 3)), zf1, o, 0, 0, 0);
    o = MFMA(*(const bf16x8*)(wrow + 32 * ((w + 2) & 3)), zf2, o, 0, 0, 0);
    o = MFMA(*(const bf16x8*)(wrow + 32 * ((w + 3) & 3)), zf3, o, 0, 0, 0);
    *(f32x4*)&out[(size_t)(r0 + l15) * Vn + 16 * w + 4 * lg] = o;
  }
}

// ---------------- fp32 fallback (no workspace needed) ----------------

__global__ __launch_bounds__(256, 1) void rnn_mfma(
    const float* __restrict__ seq, const float* __restrict__ W_in,
    const float* __restrict__ b_in, const float* __restrict__ W_h,
    const float* __restrict__ b_h, const float* __restrict__ W_out,
    const float* __restrict__ b_out, float* __restrict__ out) {
  __shared__ __align__(16) unsigned short hb[2][16][136];

  const int tid = threadIdx.x;
  const int w   = tid >> 6;
  const int l   = tid & 63;
  const int l15 = l & 15;
  const int lg  = l >> 4;
  const int r0  = blockIdx.x * 16;

  bf16x8 Bw[2][6];
  float bcl[2];
#pragma unroll
  for (int n = 0; n < 2; ++n) {
    const int j = 32 * w + 16 * n + l15;
    const float* whr = W_h + j * (2 * En);
    float b = b_h[j];
    for (int e = 0; e < En; ++e) b = fmaf(b_in[e], whr[e], b);
    bcl[n] = b;
#pragma unroll
    for (int kt = 0; kt < 6; ++kt) {
      float v[8];
#pragma unroll
      for (int i = 0; i < 8; ++i) {
        const int k = kt * 32 + lg * 8 + i;
        if (k < Vn) {
          float s = 0.f;
          for (int e = 0; e < En; ++e) s = fmaf(W_in[e * Vn + k], whr[e], s);
          v[i] = s;
        } else {
          v[i] = whr[Vn + k];
        }
      }
      Bw[n][kt] = pack8(v);
    }
  }

  for (int i = tid; i < 2 * 16 * 136; i += 256) ((unsigned short*)hb)[i] = 0;

  const float* sq = seq + ((size_t)(r0 + l15) * Ln) * Vn + lg * 8;
  f32x4 sbuf[4][4];

#define SEQ_PF(BI, T)                                                 \
  { const int tp = ((T) < Ln) ? (T) : (Ln - 1);                       \
    const f32x4* p0 = (const f32x4*)(sq + (size_t)tp * Vn);           \
    const f32x4* p1 = (const f32x4*)(sq + (size_t)tp * Vn + 32);      \
    sbuf[BI][0] = p0[0]; sbuf[BI][1] = p0[1];                         \
    sbuf[BI][2] = p1[0]; sbuf[BI][3] = p1[1]; }

  SEQ_PF(0, 0)
  SEQ_PF(1, 1)
  SEQ_PF(2, 2)
  __syncthreads();

#define PHASE(P)                                                              \
  {                                                                           \
    const int cb = (P) & 1, nb = cb ^ 1;                                      \
    const bf16x8 h0 = *(const bf16x8*)&hb[cb][l15][lg * 8];                   \
    const bf16x8 h1 = *(const bf16x8*)&hb[cb][l15][32 + lg * 8];              \
    const bf16x8 h2 = *(const bf16x8*)&hb[cb][l15][64 + lg * 8];              \
    const bf16x8 h3 = *(const bf16x8*)&hb[cb][l15][96 + lg * 8];              \
    SEQ_PF(((P) + 3) & 3, t + (P) + 3);                                       \
    float v0[8], v1[8];                                                       \
    _Pragma("unroll") for (int i = 0; i < 4; ++i) {                           \
      v0[i] = sbuf[(P)][0][i]; v0[4 + i] = sbuf[(P)][1][i];                   \
      v1[i] = sbuf[(P)][2][i]; v1[4 + i] = sbuf[(P)][3][i];                   \
    }                                                                         \
    const bf16x8 a0 = pack8(v0), a1 = pack8(v1);                              \
    f32x4 p0a = {bcl[0], bcl[0], bcl[0], bcl[0]};                             \
    f32x4 p1a = {bcl[1], bcl[1], bcl[1], bcl[1]};                             \
    f32x4 q0a = {0.f, 0.f, 0.f, 0.f}, q1a = {0.f, 0.f, 0.f, 0.f};             \
    p0a = MFMA(a0, Bw[0][0], p0a, 0, 0, 0);                                   \
    p1a = MFMA(a0, Bw[1][0], p1a, 0, 0, 0);                                   \
    p0a = MFMA(a1, Bw[0][1], p0a, 0, 0, 0);                                   \
    p1a = MFMA(a1, Bw[1][1], p1a, 0, 0, 0);                                   \
    p0a = MFMA(h0, Bw[0][2], p0a, 0, 0, 0);                                   \
    p1a = MFMA(h0, Bw[1][2], p1a, 0, 0, 0);                                   \
    q0a = MFMA(h2, Bw[0][4], q0a, 0, 0, 0);                                   \
    q1a = MFMA(h2, Bw[1][4], q1a, 0, 0, 0);                                   \
    p0a = MFMA(h1, Bw[0][3], p0a, 0, 0, 0);                                   \
    p1a = MFMA(h1, Bw[1][3], p1a, 0, 0, 0);                                   \
    q0a = MFMA(h3, Bw[0][5], q0a, 0, 0, 0);                                   \
    q1a = MFMA(h3, Bw[1][5], q1a, 0, 0, 0);                                   \
    const int j0 = 32 * w + l15, j1 = j0 + 16, rr = 4 * lg;                   \
    _Pragma("unroll") for (int i = 0; i < 4; ++i) {                           \
      hb[nb][rr + i][j0] = (unsigned short)f2b(fmaxf(p0a[i] + q0a[i], 0.f));  \
      hb[nb][rr + i][j1] = (unsigned short)f2b(fmaxf(p1a[i] + q1a[i], 0.f));  \
    }                                                                         \
    asm volatile("s_waitcnt lgkmcnt(0)" ::: "memory");                        \
    __builtin_amdgcn_s_barrier();                                             \
    asm volatile("" ::: "memory");                                            \
  }

#pragma unroll 1
  for (int t = 0; t < Ln; t += 4) {
    PHASE(0)
    PHASE(1)
    PHASE(2)
    PHASE(3)
  }
#undef PHASE
#undef SEQ_PF

  const int orow = tid >> 4;
  const int oc   = (tid & 15) * 4;
  float o0 = b_out[oc], o1 = b_out[oc + 1], o2 = b_out[oc + 2], o3 = b_out[oc + 3];
  const float* w0 = W_out + (size_t)(oc + 0) * En;
  const float* w1 = W_out + (size_t)(oc + 1) * En;
  const float* w2 = W_out + (size_t)(oc + 2) * En;
  const float* w3 = W_out + (size_t)(oc + 3) * En;
#pragma unroll 8
  for (int k = 0; k < En; ++k) {
    const float hv = b2f(hb[0][orow][k]);
    o0 = fmaf(hv, w0[k], o0);
    o1 = fmaf(hv, w1[k], o1);
    o2 = fmaf(hv, w2[k], o2);
    o3 = fmaf(hv, w3[k], o3);
  }
  *(float4*)&out[(size_t)(r0 + orow) * Vn + oc] = make_float4(o0, o1, o2, o3);
}

extern "C" void kernel_launch(void* const* d_in, const int* in_sizes, int n_in,
                              void* d_out, int out_size, void* d_ws, size_t ws_size,
                              hipStream_t stream) {
  const float* seq   = (const float*)d_in[0];
  const float* W_in  = (const float*)d_in[1];
  const float* b_in  = (const float*)d_in[2];
  const float* W_h   = (const float*)d_in[3];
  const float* b_h   = (const float*)d_in[4];
  const float* W_out = (const float*)d_in[5];
  const float* b_out = (const float*)d_in[6];
  float* out = (float*)d_out;

  if (ws_size >= SP_WS) {
    unsigned short* sp    = (unsigned short*)d_ws;
    unsigned short* wall2 = (unsigned short*)((char*)d_ws + SP_BYTES);
    float* bc             = (float*)((char*)d_ws + SP_BYTES + WALLB_BYTES);
    unsigned short* woutp = (unsigned short*)((char*)d_ws + SP_BYTES + WALLB_BYTES + BC_BYTES);
    rnn_setup2<<<En, Kc, 0, stream>>>(W_in, b_in, W_h, b_h, wall2, bc);
    wout_setup<<<Vn, En, 0, stream>>>(W_out, woutp);
    sp_pre<<<1024, 256, 0, stream>>>(seq, wall2, bc, sp);
    rnn_sp<<<Bn / 16, 256, 0, stream>>>(sp, wall2, woutp, b_out, out);
  } else if (ws_size >= FAST_WS2) {
    unsigned short* seqb  = (unsigned short*)d_ws;
    unsigned short* wall2 = (unsigned short*)((char*)d_ws + SEQB_BYTES);
    float* bc             = (float*)((char*)d_ws + SEQB_BYTES + WALLB_BYTES);
    unsigned short* woutp = (unsigned short*)((char*)d_ws + SEQB_BYTES + WALLB_BYTES + BC_BYTES);
    seq_cvt<<<2048, 256, 0, stream>>>(seq, seqb);
    rnn_setup2<<<En, Kc, 0, stream>>>(W_in, b_in, W_h, b_h, wall2, bc);
    wout_setup<<<Vn, En, 0, stream>>>(W_out, woutp);
    rnn_quad<<<Bn / 16, 256, 0, stream>>>(seqb, wall2, bc, woutp, b_out, out);
  } else {
    rnn_mfma<<<Bn / 16, 256, 0, stream>>>(seq, W_in, b_in, W_h, b_h, W_out, b_out, out);
  }
}